// Round 11
// baseline (315.772 us; speedup 1.0000x reference)
//
#include <hip/hip_runtime.h>
#include <hip/hip_fp16.h>
#include <stdint.h>

#define N_ROWS 100000
#define DCOLS 512
#define BN_EPS 1e-3f
#define PB 256

typedef __attribute__((ext_vector_type(8))) _Float16 f16x8;
typedef __attribute__((ext_vector_type(4))) float f32x4;
typedef __attribute__((ext_vector_type(4))) unsigned short u16x4;
typedef __attribute__((ext_vector_type(4))) unsigned int u32x4;

__device__ inline float fast_tanh(float x) {
  // tanh(x) = 1 - 2/(e^{2x}+1); v_rcp instead of full-precision div sequence
  float e = __expf(2.0f * x);
  return 1.0f - 2.0f * __builtin_amdgcn_rcpf(e + 1.0f);
}
__device__ inline void gld16(const void* g, void* l) {
  __builtin_amdgcn_global_load_lds(
      (const __attribute__((address_space(1))) void*)g,
      (__attribute__((address_space(3))) void*)l, 16, 0, 0);
}
__device__ inline unsigned int h2u(__half2 h) {
  unsigned int u;
  __builtin_memcpy(&u, &h, 4);
  return u;
}
__device__ inline f16x8 u2f(const u32x4& u) {
  f16x8 h;
  __builtin_memcpy(&h, &u, 16);
  return h;
}

// convert 8 raw floats to fp16 (rn)
__device__ inline f16x8 cvt8h(const float4& v0, const float4& v1) {
  __half2 h0 = __floats2half2_rn(v0.x, v0.y);
  __half2 h1 = __floats2half2_rn(v0.z, v0.w);
  __half2 h2 = __floats2half2_rn(v1.x, v1.y);
  __half2 h3 = __floats2half2_rn(v1.z, v1.w);
  u32x4 hi = (u32x4){h2u(h0), h2u(h1), h2u(h2), h2u(h3)};
  return u2f(hi);
}

// ---------------- K1: per-column partial sums (deterministic) --------------
__global__ __launch_bounds__(256) void k_stats_partial(
    const float* __restrict__ x1, const float* __restrict__ x2,
    float* __restrict__ psum, float* __restrict__ psq) {
  const int CH = (N_ROWS + PB - 1) / PB;  // 391
  int bx = blockIdx.x;
  int arr = blockIdx.y;
  const float* x = arr ? x2 : x1;
  int r0 = bx * CH;
  int r1 = min(N_ROWS, r0 + CH);
  int c0 = threadIdx.x * 2;
  float s0 = 0.f, s1 = 0.f, q0 = 0.f, q1 = 0.f;
#pragma unroll 8
  for (int r = r0; r < r1; ++r) {
    float2 v = *(const float2*)(x + (size_t)r * DCOLS + c0);
    s0 += v.x; s1 += v.y;
    q0 += v.x * v.x; q1 += v.y * v.y;
  }
  size_t base = ((size_t)(arr * PB + bx)) * DCOLS + c0;
  psum[base] = s0; psum[base + 1] = s1;
  psq[base]  = q0; psq[base + 1]  = q1;
}

// ---------------- K2: finalize -> (scale, -mean*scale); zero cvec ----------
__global__ __launch_bounds__(512) void k_stats_final(
    const float* __restrict__ psum, const float* __restrict__ psq,
    float* __restrict__ stats, float* __restrict__ cvec) {
  int a = blockIdx.x;
  int c = threadIdx.x;
  if (a == 0) cvec[c] = 0.f;  // zero accumulator for fused-c in k_prepw
  float sa[8], qa[8];
#pragma unroll
  for (int u = 0; u < 8; ++u) { sa[u] = 0.f; qa[u] = 0.f; }
  for (int b = 0; b < PB; b += 8) {
#pragma unroll
    for (int u = 0; u < 8; ++u) {
      size_t base = ((size_t)(a * PB + b + u)) * DCOLS + c;
      sa[u] += psum[base];
      qa[u] += psq[base];
    }
  }
  float s = ((sa[0]+sa[1])+(sa[2]+sa[3]))+((sa[4]+sa[5])+(sa[6]+sa[7]));
  float q = ((qa[0]+qa[1])+(qa[2]+qa[3]))+((qa[4]+qa[5])+(qa[6]+qa[7]));
  float inv = 1.0f / (float)N_ROWS;
  float mean = s * inv;
  float var = q * inv - mean * mean;
  float scale = rsqrtf(var + BN_EPS);
  stats[a * 1024 + c] = scale;
  stats[a * 1024 + 512 + c] = -mean * scale;
}

// ------- K3: W' = diag(s1)*W -> fp16 fragment order + fused c atomics ------
// wf layout: [slice=k>>5 (0..15)][gcol=j>>4 (0..31)][lane] of u32x4 (16B)
__global__ __launch_bounds__(256) void k_prepw(
    const float* __restrict__ wk, const float* __restrict__ stats,
    u32x4* __restrict__ wf, float* __restrict__ cvec) {
  int gid = blockIdx.x * 256 + threadIdx.x;  // 0..32767
  int j = gid & 511;
  int kg = gid >> 9;   // 0..63
  int k0 = kg * 8;
  const float* negms1 = stats + 512;
  unsigned short h[8];
  float cacc = 0.f;
#pragma unroll
  for (int u = 0; u < 8; ++u) {
    float wr = wk[(size_t)(k0 + u) * DCOLS + j];
    cacc += negms1[k0 + u] * wr;
    float w = wr * stats[k0 + u];  // scale1[k]
    __half hh = __float2half_rn(w);
    h[u] = __half_as_ushort(hh);
  }
  atomicAdd(cvec + j, cacc);
  int slice = k0 >> 5;
  int lr = (k0 >> 3) & 3;
  int lane = (lr << 4) | (j & 15);
  int g = j >> 4;
  int idx = slice * 2048 + g * 64 + lane;
  u16x4* ph = (u16x4*)&wf[idx];
  u16x4 h0 = {h[0], h[1], h[2], h[3]};
  u16x4 h1 = {h[4], h[5], h[6], h[7]};
  ph[0] = h0; ph[1] = h1;
}

// ---------------- K4: fused x1 @ W' + c -> gate -> out ---------------------
// OCCUPANCY round: R10 diagnosis = latency-bound (all pipes <35%, occ 39%,
// work-halving gained only 5%). Target 3 blocks/CU (6 waves/SIMD):
//  - BK=64, 8 windows (R9: 4 vs 8 windows is a wash) -> B dbuf 2x16KB=32KB,
//    3 blocks use 96KB <= 160KB.
//  - quarter-step rolling A (avA/avB = 2 float4 each, 16 regs) + bf in two
//    chunks of 4 (16 regs live) -> ~72-80 regs incl. 32 AGPR acc.
//  - __launch_bounds__(512, 6) caps at 512/6 = 85 regs.
// Window s issue order: [avA(prev) in flight][avB: loadA kk1][gld16 x2];
// waits: vmcnt(4) -> avA landed; vmcnt(2) -> avB landed (gld16 stay);
// vmcnt(2) -> gld16 landed before barrier (avA(s+1) stays). Exact drains,
// never over-wait. K-order 0,32,64,... identical to R10 -> bitwise-same
// accumulation: absmax must be exactly 0.004394531 (canary).
__global__ __launch_bounds__(512, 6) void k_main(
    const float* __restrict__ x1, const float* __restrict__ x2,
    const float* __restrict__ stats, const float* __restrict__ cvec,
    const u32x4* __restrict__ wf, float* __restrict__ out) {
  __shared__ char smem[32768];  // B dbuf: 2 x 16KB (16 frags x 1KB)

  const int tid = threadIdx.x;
  const int lane = tid & 63;
  const int wv = tid >> 6;   // 0..7, wave owns rows [wv*16, wv*16+16)
  const int ra = lane & 15;
  const int rq = lane >> 4;

  // XCD-contiguous bijective map: 3128 = 8 * 391; col-quarters adjacent.
  const int xcd = blockIdx.x & 7;
  const int wgid = xcd * 391 + (blockIdx.x >> 3);
  const int panel = wgid >> 2;      // 0..781
  const int q = wgid & 3;           // col quarter
  const int row0 = panel * 128;
  const int col0 = q * 128;

  // A fragment base: lane holds row (wv*16+ra), k = s*64 + kk*32 + rq*8 + e
  int arow = row0 + wv * 16 + ra;
  arow = min(arow, N_ROWS - 1);  // clamp: duplicate rows, outputs guarded
  const float* abase = x1 + (size_t)arow * DCOLS + rq * 8;

  // B staging: 2 gld16 per wave per window; id = wv*2+e in 0..15 = kk*8+g
  const u32x4* bsrc[2];
  int bdst[2];
#pragma unroll
  for (int e = 0; e < 2; ++e) {
    int id = wv * 2 + e;
    int kk = id >> 3, g = id & 7;
    bsrc[e] = wf + (size_t)kk * 2048 + (size_t)(q * 8 + g) * 64 + lane;
    bdst[e] = id * 1024;
  }

  // acc init with folded BN column constant
  f32x4 acc[8];
#pragma unroll
  for (int g = 0; g < 8; ++g) {
    float cj = cvec[col0 + g * 16 + ra];
    acc[g] = (f32x4){cj, cj, cj, cj};
  }

  float4 avA[2], avB[2];  // rolling quarter-step buffers (8 VGPR each)

  auto stageB = [&](int s, int buf) {
#pragma unroll
    for (int e = 0; e < 2; ++e)
      gld16(bsrc[e] + (size_t)s * 2 * 2048, smem + buf * 16384 + bdst[e]);
  };
  // load one kk-slice of A (32 k-values): 2 float4
  auto loadA = [&](int s, int kk, float4* av) {
    const float* p = abase + s * 64 + kk * 32;
    av[0] = *(const float4*)(p);
    av[1] = *(const float4*)(p + 4);
  };
  // one kk-slice: 8 bf reads in 2 chunks of 4, srcA-constant MFMA bursts
  auto computeSlice = [&](int p, int kk, const float4* av) {
    f16x8 ah = cvt8h(av[0], av[1]);
    f16x8 bf[4];
#pragma unroll
    for (int g = 0; g < 4; ++g)
      bf[g] = *(const f16x8*)(smem + p * 16384 + (kk * 8 + g) * 1024 +
                              lane * 16);
    __builtin_amdgcn_s_setprio(1);
#pragma unroll
    for (int g = 0; g < 4; ++g)
      acc[g] = __builtin_amdgcn_mfma_f32_16x16x32_f16(ah, bf[g], acc[g],
                                                      0, 0, 0);
    __builtin_amdgcn_s_setprio(0);
#pragma unroll
    for (int g = 0; g < 4; ++g)
      bf[g] = *(const f16x8*)(smem + p * 16384 + (kk * 8 + 4 + g) * 1024 +
                              lane * 16);
    __builtin_amdgcn_s_setprio(1);
#pragma unroll
    for (int g = 0; g < 4; ++g)
      acc[4 + g] = __builtin_amdgcn_mfma_f32_16x16x32_f16(ah, bf[g],
                                                          acc[4 + g], 0, 0, 0);
    __builtin_amdgcn_s_setprio(0);
  };

  // ---- prologue: B(0) + avA(0,kk0); full drain ----
  stageB(0, 0);
  asm volatile("" ::: "memory");
  loadA(0, 0, avA);
  asm volatile("s_waitcnt vmcnt(0)" ::: "memory");
  __builtin_amdgcn_s_barrier();
  __builtin_amdgcn_sched_barrier(0);

#pragma unroll
  for (int s = 0; s < 8; ++s) {
    const int p = s & 1;
    // issue order this window: [avA(s) maybe in flight] avB, gld16
    loadA(s, 1, avB);
    asm volatile("" ::: "memory");
    if (s < 7) stageB(s + 1, p ^ 1);
    __builtin_amdgcn_sched_barrier(0);

    // avA(s) landed (2 oldest); avB + gld16 stay in flight
    asm volatile("s_waitcnt vmcnt(4)" ::: "memory");
    __builtin_amdgcn_sched_barrier(0);
    computeSlice(p, 0, avA);  // kk0

    // avB landed; gld16 stay
    asm volatile("s_waitcnt vmcnt(2)" ::: "memory");
    __builtin_amdgcn_sched_barrier(0);
    if (s < 7) loadA(s + 1, 0, avA);
    __builtin_amdgcn_sched_barrier(0);
    computeSlice(p, 1, avB);  // kk1

    if (s < 7) {
      // gld16(s+1) landed before barrier; avA(s+1) stays in flight
      asm volatile("s_waitcnt vmcnt(2)" ::: "memory");
      __builtin_amdgcn_s_barrier();
      __builtin_amdgcn_sched_barrier(0);
    }
  }

  // ---- epilogue: gate + combine + tanh ----
  const float* scale1 = stats;
  const float* negms1 = stats + 512;
  const float* scale2 = stats + 1024;
  const float* negms2 = stats + 1536;

  float s1j[8], n1j[8], s2j[8], n2j[8];
#pragma unroll
  for (int g = 0; g < 8; ++g) {
    int j = col0 + g * 16 + ra;
    s1j[g] = scale1[j]; n1j[g] = negms1[j];
    s2j[g] = scale2[j]; n2j[g] = negms2[j];
  }
#pragma unroll
  for (int r = 0; r < 4; ++r) {
    int n = row0 + wv * 16 + rq * 4 + r;
    if (n < N_ROWS) {
#pragma unroll
      for (int g = 0; g < 8; ++g) {
        int j = col0 + g * 16 + ra;
        float c = acc[g][r];
        float tt = fast_tanh(c);
        float gt = fmaxf(tt, 0.0f);
        size_t idx = (size_t)n * DCOLS + j;
        float b1v = fmaf(x1[idx], s1j[g], n1j[g]);
        float b2v = fmaf(x2[idx], s2j[g], n2j[g]);
        out[idx] = fast_tanh(b2v + gt * (b1v - b2v));
      }
    }
  }
}

extern "C" void kernel_launch(void* const* d_in, const int* in_sizes, int n_in,
                              void* d_out, int out_size, void* d_ws, size_t ws_size,
                              hipStream_t stream) {
  const float* x1 = (const float*)d_in[0];
  const float* x2 = (const float*)d_in[1];
  const float* wk = (const float*)d_in[2];
  float* out = (float*)d_out;
  char* ws = (char*)d_ws;

  if (ws_size < (size_t)(4u << 20)) return;

  float* psum  = (float*)ws;                               // 1MB
  float* psq   = (float*)(ws + (1 << 20));                 // 1MB
  float* stats = (float*)(ws + (2 << 20));                 // 8KB
  float* cvec  = (float*)(ws + (2 << 20) + (160 << 10));   // 2KB
  u32x4* wf    = (u32x4*)(ws + (3 << 20));                 // 512KB

  k_stats_partial<<<dim3(PB, 2), 256, 0, stream>>>(x1, x2, psum, psq);
  k_stats_final<<<2, 512, 0, stream>>>(psum, psq, stats, cvec);
  k_prepw<<<128, 256, 0, stream>>>(wk, stats, wf, cvec);

  const int nblocks = 8 * 391;  // 782 panels x 4 col-quarters
  k_main<<<nblocks, 512, 0, stream>>>(x1, x2, stats, cvec, wf, out);
}

// Round 12
// 288.445 us; speedup vs baseline: 1.0947x; 1.0947x over previous
//
#include <hip/hip_runtime.h>
#include <hip/hip_fp16.h>
#include <stdint.h>

#define N_ROWS 100000
#define DCOLS 512
#define BN_EPS 1e-3f
#define PB 256

typedef __attribute__((ext_vector_type(8))) _Float16 f16x8;
typedef __attribute__((ext_vector_type(4))) float f32x4;
typedef __attribute__((ext_vector_type(4))) unsigned short u16x4;
typedef __attribute__((ext_vector_type(4))) unsigned int u32x4;

__device__ inline float fast_tanh(float x) {
  // tanh(x) = 1 - 2/(e^{2x}+1); v_rcp instead of full-precision div sequence
  float e = __expf(2.0f * x);
  return 1.0f - 2.0f * __builtin_amdgcn_rcpf(e + 1.0f);
}
__device__ inline void gld16(const void* g, void* l) {
  __builtin_amdgcn_global_load_lds(
      (const __attribute__((address_space(1))) void*)g,
      (__attribute__((address_space(3))) void*)l, 16, 0, 0);
}
__device__ inline unsigned int h2u(__half2 h) {
  unsigned int u;
  __builtin_memcpy(&u, &h, 4);
  return u;
}
__device__ inline f16x8 u2f(const u32x4& u) {
  f16x8 h;
  __builtin_memcpy(&h, &u, 16);
  return h;
}

// convert 8 raw floats to fp16 (single precision-level, rn)
__device__ inline f16x8 cvt8h(const float4& v0, const float4& v1) {
  __half2 h0 = __floats2half2_rn(v0.x, v0.y);
  __half2 h1 = __floats2half2_rn(v0.z, v0.w);
  __half2 h2 = __floats2half2_rn(v1.x, v1.y);
  __half2 h3 = __floats2half2_rn(v1.z, v1.w);
  u32x4 hi = (u32x4){h2u(h0), h2u(h1), h2u(h2), h2u(h3)};
  return u2f(hi);
}

// ---------------- K1: per-column partial sums (deterministic) --------------
__global__ __launch_bounds__(256) void k_stats_partial(
    const float* __restrict__ x1, const float* __restrict__ x2,
    float* __restrict__ psum, float* __restrict__ psq) {
  const int CH = (N_ROWS + PB - 1) / PB;  // 391
  int bx = blockIdx.x;
  int arr = blockIdx.y;
  const float* x = arr ? x2 : x1;
  int r0 = bx * CH;
  int r1 = min(N_ROWS, r0 + CH);
  int c0 = threadIdx.x * 2;
  float s0 = 0.f, s1 = 0.f, q0 = 0.f, q1 = 0.f;
#pragma unroll 8
  for (int r = r0; r < r1; ++r) {
    float2 v = *(const float2*)(x + (size_t)r * DCOLS + c0);
    s0 += v.x; s1 += v.y;
    q0 += v.x * v.x; q1 += v.y * v.y;
  }
  size_t base = ((size_t)(arr * PB + bx)) * DCOLS + c0;
  psum[base] = s0; psum[base + 1] = s1;
  psq[base]  = q0; psq[base + 1]  = q1;
}

// ---------------- K2: finalize -> (scale, -mean*scale); zero cvec ----------
__global__ __launch_bounds__(512) void k_stats_final(
    const float* __restrict__ psum, const float* __restrict__ psq,
    float* __restrict__ stats, float* __restrict__ cvec) {
  int a = blockIdx.x;
  int c = threadIdx.x;
  if (a == 0) cvec[c] = 0.f;  // zero accumulator for fused-c in k_prepw
  float sa[8], qa[8];
#pragma unroll
  for (int u = 0; u < 8; ++u) { sa[u] = 0.f; qa[u] = 0.f; }
  for (int b = 0; b < PB; b += 8) {
#pragma unroll
    for (int u = 0; u < 8; ++u) {
      size_t base = ((size_t)(a * PB + b + u)) * DCOLS + c;
      sa[u] += psum[base];
      qa[u] += psq[base];
    }
  }
  float s = ((sa[0]+sa[1])+(sa[2]+sa[3]))+((sa[4]+sa[5])+(sa[6]+sa[7]));
  float q = ((qa[0]+qa[1])+(qa[2]+qa[3]))+((qa[4]+qa[5])+(qa[6]+qa[7]));
  float inv = 1.0f / (float)N_ROWS;
  float mean = s * inv;
  float var = q * inv - mean * mean;
  float scale = rsqrtf(var + BN_EPS);
  stats[a * 1024 + c] = scale;
  stats[a * 1024 + 512 + c] = -mean * scale;
}

// ------- K3: W' = diag(s1)*W -> fp16 fragment order + fused c atomics ------
// wf layout: [slice=k>>5 (0..15)][gcol=j>>4 (0..31)][lane] of u32x4 (16B)
__global__ __launch_bounds__(256) void k_prepw(
    const float* __restrict__ wk, const float* __restrict__ stats,
    u32x4* __restrict__ wf, float* __restrict__ cvec) {
  int gid = blockIdx.x * 256 + threadIdx.x;  // 0..32767
  int j = gid & 511;
  int kg = gid >> 9;   // 0..63
  int k0 = kg * 8;
  const float* negms1 = stats + 512;
  unsigned short h[8];
  float cacc = 0.f;
#pragma unroll
  for (int u = 0; u < 8; ++u) {
    float wr = wk[(size_t)(k0 + u) * DCOLS + j];
    cacc += negms1[k0 + u] * wr;
    float w = wr * stats[k0 + u];  // scale1[k]
    __half hh = __float2half_rn(w);
    h[u] = __half_as_ushort(hh);
  }
  atomicAdd(cvec + j, cacc);
  int slice = k0 >> 5;
  int lr = (k0 >> 3) & 3;
  int lane = (lr << 4) | (j & 15);
  int g = j >> 4;
  int idx = slice * 2048 + g * 64 + lane;
  u16x4* ph = (u16x4*)&wf[idx];
  u16x4 h0 = {h[0], h[1], h[2], h[3]};
  u16x4 h1 = {h[4], h[5], h[6], h[7]};
  ph[0] = h0; ph[1] = h1;
}

// ---------------- K4: fused x1 @ W' + c -> gate -> out ---------------------
// R10 CHAMPION, verbatim (measured 209.7us k_main / 292.4us total), plus
// nontemporal output stores (write-once stream; keep x1/x2 lines in L2/L3).
// Structure: BK=128, 4 windows, single-fp16 A (absmax 0.004394531 verified),
// rotating half-step A buffers, srcA-constant MFMA bursts, one barrier per
// window with exact counted-vmcnt drains. Session evidence (R1-R11): barrier
// count 16/8/4/0, occupancy 2/3 blocks-per-CU, 16/32-row waves all measured
// worse or equal; this is the empirical optimum of the explored space.
__global__ __launch_bounds__(512, 4) void k_main(
    const float* __restrict__ x1, const float* __restrict__ x2,
    const float* __restrict__ stats, const float* __restrict__ cvec,
    const u32x4* __restrict__ wf, float* __restrict__ out) {
  __shared__ char smem[65536];  // B dbuf: 2 x 32KB (32 frags x 1KB)

  const int tid = threadIdx.x;
  const int lane = tid & 63;
  const int wv = tid >> 6;   // 0..7, wave owns rows [wv*16, wv*16+16)
  const int ra = lane & 15;
  const int rq = lane >> 4;

  // XCD-contiguous bijective map: 3128 = 8 * 391; col-quarters adjacent.
  const int xcd = blockIdx.x & 7;
  const int wgid = xcd * 391 + (blockIdx.x >> 3);
  const int panel = wgid >> 2;      // 0..781
  const int q = wgid & 3;           // col quarter
  const int row0 = panel * 128;
  const int col0 = q * 128;

  // A fragment base: lane holds row (wv*16+ra), k = s*128 + kk*32 + rq*8 + e
  int arow = row0 + wv * 16 + ra;
  arow = min(arow, N_ROWS - 1);  // clamp: duplicate rows, outputs guarded
  const float* abase = x1 + (size_t)arow * DCOLS + rq * 8;

  // B staging: 4 gld16 per wave per step; id = wv*4+e in 0..31 = sl*8+g
  const u32x4* bsrc[4];
  int bdst[4];
#pragma unroll
  for (int e = 0; e < 4; ++e) {
    int id = wv * 4 + e;
    int sl = id >> 3, g = id & 7;
    bsrc[e] = wf + (size_t)sl * 2048 + (size_t)(q * 8 + g) * 64 + lane;
    bdst[e] = id * 1024;
  }

  // acc init with folded BN column constant
  f32x4 acc[8];
#pragma unroll
  for (int g = 0; g < 8; ++g) {
    float cj = cvec[col0 + g * 16 + ra];
    acc[g] = (f32x4){cj, cj, cj, cj};
  }

  float4 avA[4], avB[4];  // rotating half-step buffers (16 VGPR each)

  auto stageB = [&](int s, int buf) {
#pragma unroll
    for (int e = 0; e < 4; ++e)
      gld16(bsrc[e] + (size_t)s * 8192, smem + buf * 32768 + bdst[e]);
  };
  // half 0: kk 0,1 (k-offsets 0,32); half 1: kk 2,3 (k-offsets 64,96)
  auto loadA = [&](int s, int half, float4* av) {
    const float* p = abase + s * 128 + half * 64;
    av[0] = *(const float4*)(p);
    av[1] = *(const float4*)(p + 4);
    av[2] = *(const float4*)(p + 32);
    av[3] = *(const float4*)(p + 36);
  };
  // compute 2 kk-slices (kkbase, kkbase+1) of buf p from av pair
  auto computeHalf = [&](int p, int kkbase, const float4* av) {
#pragma unroll
    for (int kk2 = 0; kk2 < 2; ++kk2) {
      int kk = kkbase + kk2;
      f16x8 bf[8];
#pragma unroll
      for (int g = 0; g < 8; ++g)
        bf[g] = *(const f16x8*)(smem + p * 32768 + (kk * 8 + g) * 1024 +
                                lane * 16);
      f16x8 ah = cvt8h(av[kk2 * 2], av[kk2 * 2 + 1]);
      __builtin_amdgcn_s_setprio(1);
#pragma unroll
      for (int g = 0; g < 8; ++g)
        acc[g] = __builtin_amdgcn_mfma_f32_16x16x32_f16(ah, bf[g], acc[g],
                                                        0, 0, 0);
      __builtin_amdgcn_s_setprio(0);
    }
  };

  // ---- prologue ----
  stageB(0, 0);
  asm volatile("" ::: "memory");  // pin issue order: gld16 before A loads
  loadA(0, 0, avA);
  asm volatile("s_waitcnt vmcnt(0)" ::: "memory");
  __builtin_amdgcn_s_barrier();
  __builtin_amdgcn_sched_barrier(0);

#pragma unroll
  for (int s = 0; s < 4; ++s) {
    const int p = s & 1;
    if (s < 3) stageB(s + 1, p ^ 1);
    asm volatile("" ::: "memory");  // order: gld16 older than A loads
    loadA(s, 1, avB);
    __builtin_amdgcn_sched_barrier(0);

    computeHalf(p, 0, avA);  // kk 0,1 (avA loaded a half-step ago)

    // avB landed (and B(s+1), issued earlier, landed too)
    asm volatile("s_waitcnt vmcnt(0)" ::: "memory");
    __builtin_amdgcn_sched_barrier(0);
    if (s < 3) loadA(s + 1, 0, avA);
    __builtin_amdgcn_sched_barrier(0);

    computeHalf(p, 2, avB);  // kk 2,3

    if (s < 3) {
      // leave avA(s+1) in flight across the barrier
      asm volatile("s_waitcnt vmcnt(4)" ::: "memory");
      __builtin_amdgcn_s_barrier();
      __builtin_amdgcn_sched_barrier(0);
    }
  }

  // ---- epilogue: gate + combine + tanh; nontemporal out stores ----
  const float* scale1 = stats;
  const float* negms1 = stats + 512;
  const float* scale2 = stats + 1024;
  const float* negms2 = stats + 1536;

  float s1j[8], n1j[8], s2j[8], n2j[8];
#pragma unroll
  for (int g = 0; g < 8; ++g) {
    int j = col0 + g * 16 + ra;
    s1j[g] = scale1[j]; n1j[g] = negms1[j];
    s2j[g] = scale2[j]; n2j[g] = negms2[j];
  }
#pragma unroll
  for (int r = 0; r < 4; ++r) {
    int n = row0 + wv * 16 + rq * 4 + r;
    if (n < N_ROWS) {
#pragma unroll
      for (int g = 0; g < 8; ++g) {
        int j = col0 + g * 16 + ra;
        float c = acc[g][r];
        float tt = fast_tanh(c);
        float gt = fmaxf(tt, 0.0f);
        size_t idx = (size_t)n * DCOLS + j;
        float b1v = fmaf(x1[idx], s1j[g], n1j[g]);
        float b2v = fmaf(x2[idx], s2j[g], n2j[g]);
        float o = fast_tanh(b2v + gt * (b1v - b2v));
        __builtin_nontemporal_store(o, out + idx);
      }
    }
  }
}

extern "C" void kernel_launch(void* const* d_in, const int* in_sizes, int n_in,
                              void* d_out, int out_size, void* d_ws, size_t ws_size,
                              hipStream_t stream) {
  const float* x1 = (const float*)d_in[0];
  const float* x2 = (const float*)d_in[1];
  const float* wk = (const float*)d_in[2];
  float* out = (float*)d_out;
  char* ws = (char*)d_ws;

  if (ws_size < (size_t)(4u << 20)) return;

  float* psum  = (float*)ws;                               // 1MB
  float* psq   = (float*)(ws + (1 << 20));                 // 1MB
  float* stats = (float*)(ws + (2 << 20));                 // 8KB
  float* cvec  = (float*)(ws + (2 << 20) + (160 << 10));   // 2KB
  u32x4* wf    = (u32x4*)(ws + (3 << 20));                 // 512KB

  k_stats_partial<<<dim3(PB, 2), 256, 0, stream>>>(x1, x2, psum, psq);
  k_stats_final<<<2, 512, 0, stream>>>(psum, psq, stats, cvec);
  k_prepw<<<128, 256, 0, stream>>>(wk, stats, wf, cvec);

  const int nblocks = 8 * 391;  // 782 panels x 4 col-quarters
  k_main<<<nblocks, 512, 0, stream>>>(x1, x2, stats, cvec, wf, out);
}